// Round 1
// baseline (597.945 us; speedup 1.0000x reference)
//
#include <hip/hip_runtime.h>
#include <math.h>

// Problem constants (from reference)
#define NSENT 131072
#define NBAGS 8192
#define DIM   690
#define NCLS  53
#define PAIRS 345   // DIM/2 (float2 granularity; rows are 8B-aligned: 690*4=2760 % 8 == 0)

// ---------------------------------------------------------------------------
// Kernel 0: comb[q][d] = attention_weight[q][d] * relation_weight[q][d]
// 53*690 = 36570 elements -> tiny, L2-resident table for the main kernel.
// ---------------------------------------------------------------------------
__global__ void comb_kernel(const float* __restrict__ att,
                            const float* __restrict__ rel,
                            float* __restrict__ comb) {
    int i = blockIdx.x * 256 + threadIdx.x;
    if (i < NCLS * DIM) comb[i] = att[i] * rel[i];
}

// ---------------------------------------------------------------------------
// Main kernel: one workgroup per bag. 4 waves; each wave streams sentences
// i = start+wave, start+wave+4, ... with flash-style online softmax:
//   - x row held in registers (6 float2 per lane, 64 lanes = 690 floats)
//   - logit = dot(x_i, comb[q_i]) via wave shuffle-reduce
//   - (m, l, acc[d]) rescaled online -> x read from HBM exactly ONCE
// Then waves merge (m,l,acc) through LDS, bag_repre = acc/l, and the 53-class
// epilogue dot products run from LDS.
// ---------------------------------------------------------------------------
template <bool USE_COMB>
__global__ __launch_bounds__(256) void bag_attn_kernel(
        const float* __restrict__ x,
        const float* __restrict__ rel,
        const float* __restrict__ att,
        const float* __restrict__ bias,
        const int*   __restrict__ query,
        const int*   __restrict__ scope,
        const float* __restrict__ comb,
        float*       __restrict__ out) {
    const int b     = blockIdx.x;
    const int tid   = threadIdx.x;
    const int wave  = tid >> 6;
    const int lane  = tid & 63;

    const int start = scope[b];
    const int end   = scope[b + 1];

    // online-softmax state (per wave, distributed across lanes for acc)
    float2 acc[6];
#pragma unroll
    for (int k = 0; k < 6; ++k) acc[k] = make_float2(0.f, 0.f);
    float m = -INFINITY;
    float l = 0.f;

    for (int i = start + wave; i < end; i += 4) {
        const float2* xrow = (const float2*)(x + (size_t)i * DIM);
        const int q = query[i];

        float2 xv[6];
        float partial = 0.f;
        if (USE_COMB) {
            const float2* crow = (const float2*)(comb + (size_t)q * DIM);
#pragma unroll
            for (int k = 0; k < 6; ++k) {
                const int p = lane + 64 * k;
                if (p < PAIRS) {
                    xv[k] = xrow[p];
                    const float2 cv = crow[p];
                    partial += xv[k].x * cv.x + xv[k].y * cv.y;
                } else {
                    xv[k] = make_float2(0.f, 0.f);
                }
            }
        } else {
            const float2* rrow = (const float2*)(rel + (size_t)q * DIM);
            const float2* arow = (const float2*)(att + (size_t)q * DIM);
#pragma unroll
            for (int k = 0; k < 6; ++k) {
                const int p = lane + 64 * k;
                if (p < PAIRS) {
                    xv[k] = xrow[p];
                    const float2 rv = rrow[p];
                    const float2 av = arow[p];
                    partial += xv[k].x * rv.x * av.x + xv[k].y * rv.y * av.y;
                } else {
                    xv[k] = make_float2(0.f, 0.f);
                }
            }
        }

        // wave-wide sum (64 lanes)
#pragma unroll
        for (int off = 32; off >= 1; off >>= 1)
            partial += __shfl_xor(partial, off, 64);
        const float logit = partial;

        // online softmax update (expf(-inf - finite) == 0 covers first iter)
        const float mn    = fmaxf(m, logit);
        const float scale = expf(m - mn);
        const float e     = expf(logit - mn);
        l = l * scale + e;
#pragma unroll
        for (int k = 0; k < 6; ++k) {
            acc[k].x = acc[k].x * scale + e * xv[k].x;
            acc[k].y = acc[k].y * scale + e * xv[k].y;
        }
        m = mn;
    }

    // ---- merge the 4 waves' (m, l, acc) via LDS ----
    __shared__ float s_m[4];
    __shared__ float s_l[4];
    __shared__ float s_acc[4][DIM];   // 4*690*4B = 11040 B
    __shared__ float s_rep[DIM];      // bag representation

    if (lane == 0) { s_m[wave] = m; s_l[wave] = l; }
    __syncthreads();

    const float M = fmaxf(fmaxf(s_m[0], s_m[1]), fmaxf(s_m[2], s_m[3]));
    // this wave's rescale factor (0 if it processed no sentences)
    const float factor = (l > 0.f) ? expf(m - M) : 0.f;
#pragma unroll
    for (int k = 0; k < 6; ++k) {
        const int p = lane + 64 * k;
        if (p < PAIRS) {
            s_acc[wave][2 * p]     = acc[k].x * factor;
            s_acc[wave][2 * p + 1] = acc[k].y * factor;
        }
    }
    __syncthreads();

    float Ltot = 0.f;
#pragma unroll
    for (int w = 0; w < 4; ++w) {
        const float fw = (s_l[w] > 0.f) ? expf(s_m[w] - M) : 0.f;
        Ltot += s_l[w] * fw;
    }
    const float inv = 1.f / Ltot;

    for (int d = tid; d < DIM; d += 256) {
        s_rep[d] = (s_acc[0][d] + s_acc[1][d] + s_acc[2][d] + s_acc[3][d]) * inv;
    }
    __syncthreads();

    // ---- epilogue: out[b][c] = dot(bag_repre, rel[c]) + bias[c] ----
    for (int c = wave; c < NCLS; c += 4) {
        const float2* rrow = (const float2*)(rel + (size_t)c * DIM);
        float partial = 0.f;
#pragma unroll
        for (int k = 0; k < 6; ++k) {
            const int p = lane + 64 * k;
            if (p < PAIRS) {
                const float2 rv = rrow[p];
                partial += rv.x * s_rep[2 * p] + rv.y * s_rep[2 * p + 1];
            }
        }
#pragma unroll
        for (int off = 32; off >= 1; off >>= 1)
            partial += __shfl_xor(partial, off, 64);
        if (lane == 0) out[(size_t)b * NCLS + c] = partial + bias[c];
    }
}

extern "C" void kernel_launch(void* const* d_in, const int* in_sizes, int n_in,
                              void* d_out, int out_size, void* d_ws, size_t ws_size,
                              hipStream_t stream) {
    const float* x     = (const float*)d_in[0];   // [131072, 690]
    const float* rel   = (const float*)d_in[1];   // [53, 690]
    const float* att   = (const float*)d_in[2];   // [53, 690]
    const float* bias  = (const float*)d_in[3];   // [53]
    const int*   query = (const int*)d_in[4];     // [131072]
    const int*   scope = (const int*)d_in[5];     // [8193]
    float*       out   = (float*)d_out;           // [8192, 53]

    const size_t comb_bytes = (size_t)NCLS * DIM * sizeof(float);
    if (ws_size >= comb_bytes) {
        float* comb = (float*)d_ws;
        comb_kernel<<<(NCLS * DIM + 255) / 256, 256, 0, stream>>>(att, rel, comb);
        bag_attn_kernel<true><<<NBAGS, 256, 0, stream>>>(
            x, rel, att, bias, query, scope, comb, out);
    } else {
        bag_attn_kernel<false><<<NBAGS, 256, 0, stream>>>(
            x, rel, att, bias, query, scope, nullptr, out);
    }
}